// Round 2
// baseline (827.710 us; speedup 1.0000x reference)
//
#include <hip/hip_runtime.h>
#include <stdint.h>

#define NV 4096
#define NE 8192
#define FV 128
#define FE 64
#define FOUT 128

typedef unsigned short u16;
typedef __attribute__((ext_vector_type(8))) short short8;
typedef __attribute__((ext_vector_type(4))) float f32x4;
typedef __attribute__((ext_vector_type(4))) unsigned short u16x4;

__device__ __forceinline__ u16 f2bf(float f) {
  uint32_t u = __builtin_bit_cast(uint32_t, f);
  u += 0x7fffu + ((u >> 16) & 1u);   // round-to-nearest-even
  return (u16)(u >> 16);
}
__device__ __forceinline__ float bf2f(u16 h) {
  return __builtin_bit_cast(float, (uint32_t)h << 16);
}

#define AS1(p) ((__attribute__((address_space(1))) void*)(void*)(p))
#define AS3(p) ((__attribute__((address_space(3))) void*)(p))

// ---------------------------------------------------------------- d[e] = dot(H_e[e,:], p)
__global__ __launch_bounds__(64) void k_edge_dot(const float* __restrict__ He,
                                                 const float* __restrict__ p,
                                                 float* __restrict__ d) {
  int e = blockIdx.x;
  int l = threadIdx.x;
  float v = He[e * FE + l] * p[l];
  #pragma unroll
  for (int off = 32; off > 0; off >>= 1) v += __shfl_down(v, off);
  if (l == 0) d[e] = v;
}

// --------------------------------------- Ta = bf16(T * d[col]), Tb = bf16(T)  (both [NV][NE], K-major)
__global__ __launch_bounds__(256) void k_convert(const float* __restrict__ T,
                                                 const float* __restrict__ d,
                                                 u16* __restrict__ Ta,
                                                 u16* __restrict__ Tb) {
  size_t idx = ((size_t)blockIdx.x * 256 + threadIdx.x) * 4;
  f32x4 t = *(const f32x4*)&T[idx];
  int e = (int)(idx & (NE - 1));
  f32x4 dv = *(const f32x4*)&d[e];
  u16x4 a, b;
  a.x = f2bf(t.x * dv.x); a.y = f2bf(t.y * dv.y);
  a.z = f2bf(t.z * dv.z); a.w = f2bf(t.w * dv.w);
  b.x = f2bf(t.x); b.y = f2bf(t.y); b.z = f2bf(t.z); b.w = f2bf(t.w);
  *(u16x4*)&Ta[idx] = a;
  *(u16x4*)&Tb[idx] = b;
}

// ---------------------------- HWt[n][i] = bf16( sum_f Hv[i][f] * W[f][n] )  ([FOUT][NV], K-major for gemm_out)
__global__ __launch_bounds__(128) void k_hw(const float* __restrict__ Hv,
                                            const float* __restrict__ W,
                                            u16* __restrict__ HWt) {
  __shared__ float sh[FV];
  int i = blockIdx.x;
  int n = threadIdx.x;
  sh[n] = Hv[i * FV + n];
  __syncthreads();
  float s = 0.f;
  #pragma unroll
  for (int f = 0; f < FV; ++f) s += sh[f] * W[f * FOUT + n];
  HWt[(size_t)n * NV + i] = f2bf(s);
}

// ------------------------- out[0:NV*FOUT) = bias bcast; out[NV*FOUT:) = H_e copy (2nd tuple output)
__global__ __launch_bounds__(256) void k_init_out(float* __restrict__ out,
                                                  const float* __restrict__ bias,
                                                  const float* __restrict__ He) {
  int idx = blockIdx.x * 256 + threadIdx.x;
  if (idx < NV * FOUT) out[idx] = bias[idx & (FOUT - 1)];
  else out[idx] = He[idx - NV * FOUT];
}

// ---------------------------------------------------------------------------
// Symmetric-aware: multiplier M = (T*d) @ T^T is symmetric (mask applied after).
// Only lower-triangle tile pairs (bi >= bj): 528 of 1024 blocks.
//   phase 1 (all): adjA[tile_m+r][tile_n+c] = ((gr==gc)?1:M)*adjv[gr][gc]
//   phase 2 (bi>bj): LDS-transposed mirror write adjA[tile_n+c][tile_m+r]
// K-loop is the m97 recipe (128x128 tile, BK=32, global_load_lds w=16).
// ---------------------------------------------------------------------------
__global__ __launch_bounds__(256) void k_gemm_mult(const u16* __restrict__ Ta,
                                                   const u16* __restrict__ Tb,
                                                   const float* __restrict__ adjv,
                                                   u16* __restrict__ adjA) {
  // union: K-loop uses first 16 KB as lA/lB; epilogue reuses as 128x136 bf16 tile
  __shared__ __align__(16) u16 smem[128 * 136];
  u16* lA = smem;          // 128*32
  u16* lB = smem + 4096;   // 128*32
  u16* sT = smem;          // 128*136 (transposed tile, epilogue only)

  // decode triangular block id -> (bi, bj), bi >= bj
  int id = blockIdx.x;
  int bi = (int)((sqrtf(8.0f * (float)id + 1.0f) - 1.0f) * 0.5f);
  while ((bi + 1) * (bi + 2) / 2 <= id) ++bi;
  while (bi * (bi + 1) / 2 > id) --bi;
  int bj = id - bi * (bi + 1) / 2;

  const int K = NE;
  const int tile_m = bi * 128;
  const int tile_n = bj * 128;
  const int tid = threadIdx.x;
  const int lane = tid & 63;
  const int wave = tid >> 6;
  const int wm = (wave >> 1) * 64;
  const int wn = (wave & 1) * 64;
  const int row16 = lane & 15;
  const int quad = lane >> 4;

  f32x4 acc[4][4] = {};

  for (int k0 = 0; k0 < K; k0 += 32) {
    __syncthreads();
    #pragma unroll
    for (int r = 0; r < 2; ++r) {
      const int chunk = r * 256 + wave * 64 + lane;   // 16B chunk id, 512 per tile
      const int row = chunk >> 2;                     // 4 chunks per 32-elem row
      const int cc = chunk & 3;
      const u16* ga = Ta + ((size_t)(tile_m + row) * K + k0 + cc * 8);
      const u16* gb = Tb + ((size_t)(tile_n + row) * K + k0 + cc * 8);
      __builtin_amdgcn_global_load_lds(AS1(ga), AS3(&lA[(r * 256 + wave * 64) * 8]), 16, 0, 0);
      __builtin_amdgcn_global_load_lds(AS1(gb), AS3(&lB[(r * 256 + wave * 64) * 8]), 16, 0, 0);
    }
    __syncthreads();
    short8 a[4], b[4];
    #pragma unroll
    for (int mi = 0; mi < 4; ++mi)
      a[mi] = *(const short8*)&lA[(wm + mi * 16 + row16) * 32 + quad * 8];
    #pragma unroll
    for (int ni = 0; ni < 4; ++ni)
      b[ni] = *(const short8*)&lB[(wn + ni * 16 + row16) * 32 + quad * 8];
    #pragma unroll
    for (int mi = 0; mi < 4; ++mi)
      #pragma unroll
      for (int ni = 0; ni < 4; ++ni)
        acc[mi][ni] = __builtin_amdgcn_mfma_f32_16x16x32_bf16(a[mi], b[ni], acc[mi][ni], 0, 0, 0);
  }

  // phase 1: direct write (C/D layout: col=lane&15, row=quad*4+reg)
  #pragma unroll
  for (int mi = 0; mi < 4; ++mi) {
    #pragma unroll
    for (int ni = 0; ni < 4; ++ni) {
      const int gc = tile_n + wn + ni * 16 + row16;
      #pragma unroll
      for (int r = 0; r < 4; ++r) {
        const int gr = tile_m + wm + mi * 16 + quad * 4 + r;
        float v = acc[mi][ni][r];
        if (gr == gc) v = 1.0f;                 // diag of M1 is exactly 1 (diag blocks only)
        v *= adjv[(size_t)gr * NV + gc];
        adjA[(size_t)gr * NV + gc] = f2bf(v);
      }
    }
  }

  // phase 2: mirror write for off-diagonal blocks via LDS transpose
  if (bi != bj) {
    __syncthreads();   // K-loop ds_reads done before sT overwrites lA/lB region
    #pragma unroll
    for (int mi = 0; mi < 4; ++mi) {
      #pragma unroll
      for (int ni = 0; ni < 4; ++ni) {
        const int c = wn + ni * 16 + row16;       // tile col
        const int r0 = wm + mi * 16 + quad * 4;   // tile row base (4 consecutive)
        u16x4 pk;
        pk.x = f2bf(acc[mi][ni][0]); pk.y = f2bf(acc[mi][ni][1]);
        pk.z = f2bf(acc[mi][ni][2]); pk.w = f2bf(acc[mi][ni][3]);
        *(u16x4*)&sT[c * 136 + r0] = pk;          // sT[c][r] = M[r][c]
      }
    }
    __syncthreads();
    const int row = tid >> 1;          // tile col c = row of sT
    const int half = tid & 1;
    const size_t obase = (size_t)(tile_n + row) * NV + tile_m + half * 64;
    const u16* srow = &sT[row * 136 + half * 64];
    #pragma unroll
    for (int j = 0; j < 8; ++j) {
      short8 m8 = *(const short8*)&srow[j * 8];
      short8 o8;
      #pragma unroll
      for (int k = 0; k < 8; ++k) {
        float v = bf2f((u16)m8[k]) * adjv[obase + j * 8 + k];
        o8[k] = (short)f2bf(v);
      }
      *(short8*)&adjA[obase + j * 8] = o8;
    }
  }
}

// ---------------------------------------------------------------------------
// out[i][n] += sum_k adjA[i][k] * HWt[n][k]   (K-split, fp32 atomics;
// bias was pre-initialized by k_init_out)
// ---------------------------------------------------------------------------
#define KSPLIT 16
__global__ __launch_bounds__(256) void k_gemm_out(const u16* __restrict__ A,
                                                  const u16* __restrict__ B,
                                                  float* __restrict__ out) {
  __shared__ __align__(16) u16 lA[128 * 32];
  __shared__ __align__(16) u16 lB[128 * 32];
  const int K = NV;
  const int tile_m = blockIdx.y * 128;
  const int kbeg = blockIdx.x * (K / KSPLIT);
  const int kend = kbeg + (K / KSPLIT);
  const int tid = threadIdx.x;
  const int lane = tid & 63;
  const int wave = tid >> 6;
  const int wm = (wave >> 1) * 64;
  const int wn = (wave & 1) * 64;
  const int row16 = lane & 15;
  const int quad = lane >> 4;

  f32x4 acc[4][4] = {};

  for (int k0 = kbeg; k0 < kend; k0 += 32) {
    __syncthreads();
    #pragma unroll
    for (int r = 0; r < 2; ++r) {
      const int chunk = r * 256 + wave * 64 + lane;
      const int row = chunk >> 2;
      const int cc = chunk & 3;
      const u16* ga = A + ((size_t)(tile_m + row) * K + k0 + cc * 8);
      const u16* gb = B + ((size_t)row * K + k0 + cc * 8);   // N=128: full B tile
      __builtin_amdgcn_global_load_lds(AS1(ga), AS3(&lA[(r * 256 + wave * 64) * 8]), 16, 0, 0);
      __builtin_amdgcn_global_load_lds(AS1(gb), AS3(&lB[(r * 256 + wave * 64) * 8]), 16, 0, 0);
    }
    __syncthreads();
    short8 a[4], b[4];
    #pragma unroll
    for (int mi = 0; mi < 4; ++mi)
      a[mi] = *(const short8*)&lA[(wm + mi * 16 + row16) * 32 + quad * 8];
    #pragma unroll
    for (int ni = 0; ni < 4; ++ni)
      b[ni] = *(const short8*)&lB[(wn + ni * 16 + row16) * 32 + quad * 8];
    #pragma unroll
    for (int mi = 0; mi < 4; ++mi)
      #pragma unroll
      for (int ni = 0; ni < 4; ++ni)
        acc[mi][ni] = __builtin_amdgcn_mfma_f32_16x16x32_bf16(a[mi], b[ni], acc[mi][ni], 0, 0, 0);
  }

  #pragma unroll
  for (int mi = 0; mi < 4; ++mi) {
    #pragma unroll
    for (int ni = 0; ni < 4; ++ni) {
      const int gc = wn + ni * 16 + row16;      // tile_n = 0, N = 128
      #pragma unroll
      for (int r = 0; r < 4; ++r) {
        const int gr = tile_m + wm + mi * 16 + quad * 4 + r;
        atomicAdd(&out[(size_t)gr * FOUT + gc], acc[mi][ni][r]);
      }
    }
  }
}

extern "C" void kernel_launch(void* const* d_in, const int* in_sizes, int n_in,
                              void* d_out, int out_size, void* d_ws, size_t ws_size,
                              hipStream_t stream) {
  const float* Hv   = (const float*)d_in[0];
  const float* He   = (const float*)d_in[1];
  // d_in[2] = adj_e : unused in node_layer=True path
  const float* adjv = (const float*)d_in[3];
  const float* T    = (const float*)d_in[4];
  const float* W    = (const float*)d_in[5];
  const float* p    = (const float*)d_in[6];
  const float* bias = (const float*)d_in[7];
  float* out = (float*)d_out;

  // ws layout (~162 MB):
  //   [0,32KB) d | [1MB,2MB) HWt | [2MB,66MB) Ta | [66MB,130MB) Tb | [130MB,162MB) adjA
  char* ws = (char*)d_ws;
  float* dvec = (float*)ws;
  u16* HWt  = (u16*)(ws + ((size_t)1 << 20));
  u16* Ta   = (u16*)(ws + ((size_t)2 << 20));
  u16* Tb   = (u16*)(ws + ((size_t)2 << 20) + ((size_t)64 << 20));
  u16* adjA = (u16*)(ws + ((size_t)2 << 20) + ((size_t)128 << 20));

  k_edge_dot<<<NE, 64, 0, stream>>>(He, p, dvec);
  k_convert<<<(NV * NE) / (256 * 4), 256, 0, stream>>>(T, dvec, Ta, Tb);
  k_hw<<<NV, 128, 0, stream>>>(Hv, W, HWt);
  k_init_out<<<(NV * FOUT + NE * FE) / 256, 256, 0, stream>>>(out, bias, He);
  k_gemm_mult<<<(32 * 33) / 2, 256, 0, stream>>>(Ta, Tb, adjv, adjA);
  k_gemm_out<<<dim3(KSPLIT, NV / 128), 256, 0, stream>>>(adjA, HWt, out);
}

// Round 3
// 733.148 us; speedup vs baseline: 1.1290x; 1.1290x over previous
//
#include <hip/hip_runtime.h>
#include <stdint.h>

#define NV 4096
#define NE 8192
#define FV 128
#define FE 64
#define FOUT 128

typedef unsigned short u16;
typedef __attribute__((ext_vector_type(8))) short short8;
typedef __attribute__((ext_vector_type(4))) float f32x4;
typedef __attribute__((ext_vector_type(4))) unsigned short u16x4;

__device__ __forceinline__ u16 f2bf(float f) {
  uint32_t u = __builtin_bit_cast(uint32_t, f);
  u += 0x7fffu + ((u >> 16) & 1u);   // round-to-nearest-even
  return (u16)(u >> 16);
}
__device__ __forceinline__ float bf2f(u16 h) {
  return __builtin_bit_cast(float, (uint32_t)h << 16);
}

#define AS1(p) ((__attribute__((address_space(1))) void*)(void*)(p))
#define AS3(p) ((__attribute__((address_space(3))) void*)(p))

__device__ __forceinline__ void tri_decode(int id, int& bi, int& bj) {
  bi = (int)((sqrtf(8.0f * (float)id + 1.0f) - 1.0f) * 0.5f);
  while ((bi + 1) * (bi + 2) / 2 <= id) ++bi;
  while (bi * (bi + 1) / 2 > id) --bi;
  bj = id - bi * (bi + 1) / 2;
}

// ---------------------------------------------------------------- d[e] = dot(H_e[e,:], p)
__global__ __launch_bounds__(64) void k_edge_dot(const float* __restrict__ He,
                                                 const float* __restrict__ p,
                                                 float* __restrict__ d) {
  int e = blockIdx.x;
  int l = threadIdx.x;
  float v = He[e * FE + l] * p[l];
  #pragma unroll
  for (int off = 32; off > 0; off >>= 1) v += __shfl_down(v, off);
  if (l == 0) d[e] = v;
}

// --------------------------------------- Ta = bf16(T * d[col]), Tb = bf16(T)  (both [NV][NE], K-major)
__global__ __launch_bounds__(256) void k_convert(const float* __restrict__ T,
                                                 const float* __restrict__ d,
                                                 u16* __restrict__ Ta,
                                                 u16* __restrict__ Tb) {
  size_t idx = ((size_t)blockIdx.x * 256 + threadIdx.x) * 4;
  f32x4 t = *(const f32x4*)&T[idx];
  int e = (int)(idx & (NE - 1));
  f32x4 dv = *(const f32x4*)&d[e];
  u16x4 a, b;
  a.x = f2bf(t.x * dv.x); a.y = f2bf(t.y * dv.y);
  a.z = f2bf(t.z * dv.z); a.w = f2bf(t.w * dv.w);
  b.x = f2bf(t.x); b.y = f2bf(t.y); b.z = f2bf(t.z); b.w = f2bf(t.w);
  *(u16x4*)&Ta[idx] = a;
  *(u16x4*)&Tb[idx] = b;
}

// ---------------------------- HWt[n][i] = bf16( sum_f Hv[i][f] * W[f][n] )  ([FOUT][NV], K-major for gemm_out)
__global__ __launch_bounds__(128) void k_hw(const float* __restrict__ Hv,
                                            const float* __restrict__ W,
                                            u16* __restrict__ HWt) {
  __shared__ float sh[FV];
  int i = blockIdx.x;
  int n = threadIdx.x;
  sh[n] = Hv[i * FV + n];
  __syncthreads();
  float s = 0.f;
  #pragma unroll
  for (int f = 0; f < FV; ++f) s += sh[f] * W[f * FOUT + n];
  HWt[(size_t)n * NV + i] = f2bf(s);
}

// ------------------------- out[0:NV*FOUT) = bias bcast; out[NV*FOUT:) = H_e copy (2nd tuple output)
__global__ __launch_bounds__(256) void k_init_out(float* __restrict__ out,
                                                  const float* __restrict__ bias,
                                                  const float* __restrict__ He) {
  int idx = blockIdx.x * 256 + threadIdx.x;
  if (idx < NV * FOUT) out[idx] = bias[idx & (FOUT - 1)];
  else out[idx] = He[idx - NV * FOUT];
}

// ---------------------------------------------------------------------------
// Symmetric GEMM, K-split by 2: block bx = pair*2 + split computes the
// (bi,bj) 128x128 tile (bi>=bj) over K-half `split`, stores bf16 partial in
// raw MFMA C-layout (lane-linear, coalesced): Mp[bx][wave][frag][lane][r].
// Pure K-loop, 16 KB LDS, no epilogue.
// ---------------------------------------------------------------------------
__global__ __launch_bounds__(256) void k_gemm_sym(const u16* __restrict__ Ta,
                                                  const u16* __restrict__ Tb,
                                                  u16* __restrict__ Mp) {
  __shared__ __align__(16) u16 lA[128 * 32];
  __shared__ __align__(16) u16 lB[128 * 32];
  const int bx = blockIdx.x;
  const int pair = bx >> 1;
  const int split = bx & 1;
  int bi, bj;
  tri_decode(pair, bi, bj);

  const int K = NE;
  const int kbeg = split * (K / 2);
  const int kend = kbeg + K / 2;
  const int tile_m = bi * 128;
  const int tile_n = bj * 128;
  const int tid = threadIdx.x;
  const int lane = tid & 63;
  const int wave = tid >> 6;
  const int wm = (wave >> 1) * 64;
  const int wn = (wave & 1) * 64;
  const int row16 = lane & 15;
  const int quad = lane >> 4;

  f32x4 acc[4][4] = {};

  for (int k0 = kbeg; k0 < kend; k0 += 32) {
    __syncthreads();
    #pragma unroll
    for (int r = 0; r < 2; ++r) {
      const int chunk = r * 256 + wave * 64 + lane;   // 16B chunk id, 512 per tile
      const int row = chunk >> 2;                     // 4 chunks per 32-elem row
      const int cc = chunk & 3;
      const u16* ga = Ta + ((size_t)(tile_m + row) * K + k0 + cc * 8);
      const u16* gb = Tb + ((size_t)(tile_n + row) * K + k0 + cc * 8);
      __builtin_amdgcn_global_load_lds(AS1(ga), AS3(&lA[(r * 256 + wave * 64) * 8]), 16, 0, 0);
      __builtin_amdgcn_global_load_lds(AS1(gb), AS3(&lB[(r * 256 + wave * 64) * 8]), 16, 0, 0);
    }
    __syncthreads();
    short8 a[4], b[4];
    #pragma unroll
    for (int mi = 0; mi < 4; ++mi)
      a[mi] = *(const short8*)&lA[(wm + mi * 16 + row16) * 32 + quad * 8];
    #pragma unroll
    for (int ni = 0; ni < 4; ++ni)
      b[ni] = *(const short8*)&lB[(wn + ni * 16 + row16) * 32 + quad * 8];
    #pragma unroll
    for (int mi = 0; mi < 4; ++mi)
      #pragma unroll
      for (int ni = 0; ni < 4; ++ni)
        acc[mi][ni] = __builtin_amdgcn_mfma_f32_16x16x32_bf16(a[mi], b[ni], acc[mi][ni], 0, 0, 0);
  }

  // coalesced lane-linear partial store: wave writes 512B contiguous per frag
  u16* dst = Mp + (size_t)bx * 16384 + wave * 4096;
  #pragma unroll
  for (int mi = 0; mi < 4; ++mi) {
    #pragma unroll
    for (int ni = 0; ni < 4; ++ni) {
      const int f = mi * 4 + ni;
      u16x4 pk;
      pk.x = f2bf(acc[mi][ni][0]); pk.y = f2bf(acc[mi][ni][1]);
      pk.z = f2bf(acc[mi][ni][2]); pk.w = f2bf(acc[mi][ni][3]);
      *(u16x4*)&dst[f * 256 + lane * 4] = pk;
    }
  }
}

// ---------------------------------------------------------------------------
// Epilogue: add the two K-split partials (reads are fully coalesced since the
// thread's (wave,lane) matches the producer's), apply eye-mask and adjv,
// write direct block; for bi!=bj also the LDS-transposed mirror block.
// ---------------------------------------------------------------------------
__global__ __launch_bounds__(256) void k_mask(const u16* __restrict__ Mp,
                                              const float* __restrict__ adjv,
                                              u16* __restrict__ adjA) {
  __shared__ __align__(16) u16 sT[128 * 136];
  const int pair = blockIdx.x;
  int bi, bj;
  tri_decode(pair, bi, bj);
  const int tile_m = bi * 128;
  const int tile_n = bj * 128;
  const int tid = threadIdx.x;
  const int lane = tid & 63;
  const int wave = tid >> 6;
  const int wm = (wave >> 1) * 64;
  const int wn = (wave & 1) * 64;
  const int row16 = lane & 15;
  const int quad = lane >> 4;

  const u16* s0 = Mp + (size_t)(pair * 2) * 16384 + wave * 4096;
  const u16* s1 = s0 + 16384;

  f32x4 acc[4][4];
  #pragma unroll
  for (int mi = 0; mi < 4; ++mi) {
    #pragma unroll
    for (int ni = 0; ni < 4; ++ni) {
      const int f = mi * 4 + ni;
      u16x4 a = *(const u16x4*)&s0[f * 256 + lane * 4];
      u16x4 b = *(const u16x4*)&s1[f * 256 + lane * 4];
      acc[mi][ni][0] = bf2f(a.x) + bf2f(b.x);
      acc[mi][ni][1] = bf2f(a.y) + bf2f(b.y);
      acc[mi][ni][2] = bf2f(a.z) + bf2f(b.z);
      acc[mi][ni][3] = bf2f(a.w) + bf2f(b.w);
    }
  }

  // phase 1: direct write (C/D layout: col=lane&15, row=quad*4+reg)
  #pragma unroll
  for (int mi = 0; mi < 4; ++mi) {
    #pragma unroll
    for (int ni = 0; ni < 4; ++ni) {
      const int gc = tile_n + wn + ni * 16 + row16;
      #pragma unroll
      for (int r = 0; r < 4; ++r) {
        const int gr = tile_m + wm + mi * 16 + quad * 4 + r;
        float v = acc[mi][ni][r];
        if (gr == gc) v = 1.0f;                 // diag of M1 is exactly 1
        v *= adjv[(size_t)gr * NV + gc];
        adjA[(size_t)gr * NV + gc] = f2bf(v);
      }
    }
  }

  // phase 2: mirror write via LDS transpose (off-diagonal pairs)
  if (bi != bj) {
    #pragma unroll
    for (int mi = 0; mi < 4; ++mi) {
      #pragma unroll
      for (int ni = 0; ni < 4; ++ni) {
        const int c = wn + ni * 16 + row16;       // tile col
        const int r0 = wm + mi * 16 + quad * 4;   // tile row base (4 consecutive)
        u16x4 pk;
        pk.x = f2bf(acc[mi][ni][0]); pk.y = f2bf(acc[mi][ni][1]);
        pk.z = f2bf(acc[mi][ni][2]); pk.w = f2bf(acc[mi][ni][3]);
        *(u16x4*)&sT[c * 136 + r0] = pk;          // sT[c][r] = M[r][c]
      }
    }
    __syncthreads();
    const int row = tid >> 1;          // tile col c = row of sT
    const int half = tid & 1;
    const size_t obase = (size_t)(tile_n + row) * NV + tile_m + half * 64;
    const u16* srow = &sT[row * 136 + half * 64];
    #pragma unroll
    for (int j = 0; j < 8; ++j) {
      short8 m8 = *(const short8*)&srow[j * 8];
      short8 o8;
      #pragma unroll
      for (int k = 0; k < 8; ++k) {
        float v = bf2f((u16)m8[k]) * adjv[obase + j * 8 + k];
        o8[k] = (short)f2bf(v);
      }
      *(short8*)&adjA[obase + j * 8] = o8;
    }
  }
}

// ---------------------------------------------------------------------------
// out[i][n] += sum_k adjA[i][k] * HWt[n][k]   (K-split, fp32 atomics;
// bias was pre-initialized by k_init_out)
// ---------------------------------------------------------------------------
#define KSPLIT 16
__global__ __launch_bounds__(256) void k_gemm_out(const u16* __restrict__ A,
                                                  const u16* __restrict__ B,
                                                  float* __restrict__ out) {
  __shared__ __align__(16) u16 lA[128 * 32];
  __shared__ __align__(16) u16 lB[128 * 32];
  const int K = NV;
  const int tile_m = blockIdx.y * 128;
  const int kbeg = blockIdx.x * (K / KSPLIT);
  const int kend = kbeg + (K / KSPLIT);
  const int tid = threadIdx.x;
  const int lane = tid & 63;
  const int wave = tid >> 6;
  const int wm = (wave >> 1) * 64;
  const int wn = (wave & 1) * 64;
  const int row16 = lane & 15;
  const int quad = lane >> 4;

  f32x4 acc[4][4] = {};

  for (int k0 = kbeg; k0 < kend; k0 += 32) {
    __syncthreads();
    #pragma unroll
    for (int r = 0; r < 2; ++r) {
      const int chunk = r * 256 + wave * 64 + lane;
      const int row = chunk >> 2;
      const int cc = chunk & 3;
      const u16* ga = A + ((size_t)(tile_m + row) * K + k0 + cc * 8);
      const u16* gb = B + ((size_t)row * K + k0 + cc * 8);   // N=128: full B tile
      __builtin_amdgcn_global_load_lds(AS1(ga), AS3(&lA[(r * 256 + wave * 64) * 8]), 16, 0, 0);
      __builtin_amdgcn_global_load_lds(AS1(gb), AS3(&lB[(r * 256 + wave * 64) * 8]), 16, 0, 0);
    }
    __syncthreads();
    short8 a[4], b[4];
    #pragma unroll
    for (int mi = 0; mi < 4; ++mi)
      a[mi] = *(const short8*)&lA[(wm + mi * 16 + row16) * 32 + quad * 8];
    #pragma unroll
    for (int ni = 0; ni < 4; ++ni)
      b[ni] = *(const short8*)&lB[(wn + ni * 16 + row16) * 32 + quad * 8];
    #pragma unroll
    for (int mi = 0; mi < 4; ++mi)
      #pragma unroll
      for (int ni = 0; ni < 4; ++ni)
        acc[mi][ni] = __builtin_amdgcn_mfma_f32_16x16x32_bf16(a[mi], b[ni], acc[mi][ni], 0, 0, 0);
  }

  #pragma unroll
  for (int mi = 0; mi < 4; ++mi) {
    #pragma unroll
    for (int ni = 0; ni < 4; ++ni) {
      const int gc = wn + ni * 16 + row16;      // tile_n = 0, N = 128
      #pragma unroll
      for (int r = 0; r < 4; ++r) {
        const int gr = tile_m + wm + mi * 16 + quad * 4 + r;
        atomicAdd(&out[(size_t)gr * FOUT + gc], acc[mi][ni][r]);
      }
    }
  }
}

extern "C" void kernel_launch(void* const* d_in, const int* in_sizes, int n_in,
                              void* d_out, int out_size, void* d_ws, size_t ws_size,
                              hipStream_t stream) {
  const float* Hv   = (const float*)d_in[0];
  const float* He   = (const float*)d_in[1];
  // d_in[2] = adj_e : unused in node_layer=True path
  const float* adjv = (const float*)d_in[3];
  const float* T    = (const float*)d_in[4];
  const float* W    = (const float*)d_in[5];
  const float* p    = (const float*)d_in[6];
  const float* bias = (const float*)d_in[7];
  float* out = (float*)d_out;

  // ws layout (~195 MB):
  //   [0,32KB) d | [1MB,2MB) HWt | [2MB,66MB) Ta | [66MB,130MB) Tb
  //   [130MB,162MB) adjA | [162MB,~195MB) Mp (528 pairs x 2 splits x 32KB bf16)
  char* ws = (char*)d_ws;
  float* dvec = (float*)ws;
  u16* HWt  = (u16*)(ws + ((size_t)1 << 20));
  u16* Ta   = (u16*)(ws + ((size_t)2 << 20));
  u16* Tb   = (u16*)(ws + ((size_t)2 << 20) + ((size_t)64 << 20));
  u16* adjA = (u16*)(ws + ((size_t)2 << 20) + ((size_t)128 << 20));
  u16* Mp   = (u16*)(ws + ((size_t)2 << 20) + ((size_t)160 << 20));

  k_edge_dot<<<NE, 64, 0, stream>>>(He, p, dvec);
  k_convert<<<(NV * NE) / (256 * 4), 256, 0, stream>>>(T, dvec, Ta, Tb);
  k_hw<<<NV, 128, 0, stream>>>(Hv, W, HWt);
  k_init_out<<<(NV * FOUT + NE * FE) / 256, 256, 0, stream>>>(out, bias, He);
  k_gemm_sym<<<528 * 2, 256, 0, stream>>>(Ta, Tb, Mp);
  k_mask<<<528, 256, 0, stream>>>(Mp, adjv, adjA);
  k_gemm_out<<<dim3(KSPLIT, NV / 128), 256, 0, stream>>>(adjA, HWt, out);
}